// Round 2
// baseline (3218.378 us; speedup 1.0000x reference)
//
#include <hip/hip_runtime.h>
#include <hip/hip_bf16.h>
#include <cstdint>

#define M_ROWS 4096
#define K_DIM  768
#define N_HID  24576
#define TOPK   32
#define MAXCAND 64

// ---------------------------------------------------------------------------
// Kernel 1: acts = (A - b_pre) @ W_enc        [4096x768] x [768x24576]
// fp32 vector GEMM, 64x64 tile, BK=16, 256 threads, 4x4 per thread.
// ---------------------------------------------------------------------------
__global__ __launch_bounds__(256) void encode_gemm(
    const float* __restrict__ A, const float* __restrict__ W,
    const float* __restrict__ b_pre, float* __restrict__ acts)
{
    __shared__ float As[16][68];
    __shared__ float Bs[16][64];

    const int tid = threadIdx.x;
    const int tx = tid & 15;        // 16 threads over N
    const int ty = tid >> 4;        // 16 threads over M
    const int m0 = blockIdx.y * 64;
    const int n0 = blockIdx.x * 64;

    float acc[4][4] = {};

    for (int k0 = 0; k0 < K_DIM; k0 += 16) {
        #pragma unroll
        for (int i = 0; i < 4; ++i) {
            int e = tid + i * 256;
            int r = e >> 4, c = e & 15;
            As[c][r] = A[(size_t)(m0 + r) * K_DIM + k0 + c] - b_pre[k0 + c];
        }
        #pragma unroll
        for (int i = 0; i < 4; ++i) {
            int e = tid + i * 256;
            int r = e >> 6, c = e & 63;
            Bs[r][c] = W[(size_t)(k0 + r) * N_HID + n0 + c];
        }
        __syncthreads();

        #pragma unroll
        for (int kk = 0; kk < 16; ++kk) {
            float4 a4 = *(const float4*)&As[kk][ty * 4];
            float4 b4 = *(const float4*)&Bs[kk][tx * 4];
            float av[4] = {a4.x, a4.y, a4.z, a4.w};
            float bv[4] = {b4.x, b4.y, b4.z, b4.w};
            #pragma unroll
            for (int i = 0; i < 4; ++i)
                #pragma unroll
                for (int j = 0; j < 4; ++j)
                    acc[i][j] = fmaf(av[i], bv[j], acc[i][j]);
        }
        __syncthreads();
    }

    #pragma unroll
    for (int i = 0; i < 4; ++i) {
        float4 v = make_float4(acc[i][0], acc[i][1], acc[i][2], acc[i][3]);
        *(float4*)&acts[(size_t)(m0 + ty * 4 + i) * N_HID + n0 + tx * 4] = v;
    }
}

// ---------------------------------------------------------------------------
// Kernel 2: per-row top-32 with fp64 boundary repair, z scatter, fused decode.
// One block (256 threads) per row.
// ---------------------------------------------------------------------------
__device__ __forceinline__ uint32_t f2k(float f) {
    uint32_t b = __float_as_uint(f);
    return (b & 0x80000000u) ? ~b : (b | 0x80000000u);
}
__device__ __forceinline__ float k2f(uint32_t k) {
    return __uint_as_float((k & 0x80000000u) ? (k ^ 0x80000000u) : ~k);
}

__global__ __launch_bounds__(256) void topk_decode(
    const float* __restrict__ acts, const float* __restrict__ A,
    const float* __restrict__ W_dec, const float* __restrict__ b_pre,
    float* __restrict__ z, float* __restrict__ recon)
{
    const int row = blockIdx.x;
    const int tid = threadIdx.x;
    const float* arow = acts + (size_t)row * N_HID;

    __shared__ float    ash[K_DIM];       // A[row,:] - b_pre
    __shared__ uint32_t hist[256];
    __shared__ uint32_t sfx[256];
    __shared__ uint32_t bsel, bgt;
    __shared__ int      candN;
    __shared__ int      candIdx[MAXCAND];
    __shared__ double   candVal[MAXCAND];
    __shared__ double   partsum[4][MAXCAND];
    __shared__ int      selIdx[TOPK];
    __shared__ float    selVal[TOPK];

    // A row (for fp64 repair) into LDS
    for (int i = tid; i < K_DIM; i += 256) ash[i] = A[(size_t)row * K_DIM + i] - b_pre[i];

    // Load this row's acts as order-preserving u32 keys in registers.
    uint32_t key[96];
    #pragma unroll
    for (int i = 0; i < 24; ++i) {
        const float4 v = *(const float4*)(arow + ((size_t)(tid + i * 256) << 2));
        key[i * 4 + 0] = f2k(v.x);
        key[i * 4 + 1] = f2k(v.y);
        key[i * 4 + 2] = f2k(v.z);
        key[i * 4 + 3] = f2k(v.w);
    }

    // ---- radix select: exact fp32 key T of the 32nd largest ----
    uint32_t prefix = 0;
    uint32_t kneed = TOPK;
    for (int shift = 24; shift >= 0; shift -= 8) {
        hist[tid] = 0u;
        __syncthreads();
        #pragma unroll
        for (int i = 0; i < 96; ++i) {
            uint32_t kk = key[i];
            bool m = (shift == 24) || ((kk >> (shift + 8)) == prefix);
            if (m) atomicAdd(&hist[(kk >> shift) & 255u], 1u);
        }
        __syncthreads();
        sfx[tid] = hist[tid];
        __syncthreads();
        for (int off = 1; off < 256; off <<= 1) {
            uint32_t t = (tid + off < 256) ? sfx[tid + off] : 0u;
            __syncthreads();
            sfx[tid] += t;
            __syncthreads();
        }
        uint32_t ge = sfx[tid];
        uint32_t gt = (tid < 255) ? sfx[tid + 1] : 0u;
        if (gt < kneed && kneed <= ge) { bsel = (uint32_t)tid; bgt = gt; }
        __syncthreads();
        prefix = (prefix << 8) | bsel;
        kneed -= bgt;
        __syncthreads();
    }
    const float vT = k2f(prefix);
    // Candidate band: covers worst-case fp32 accumulation error (~3.4e-5) with
    // ~30x margin; expected ~1 extra candidate beyond the 32.
    const uint32_t keyLo = f2k(vT - 1e-3f);

    if (tid == 0) candN = 0;
    __syncthreads();
    #pragma unroll
    for (int i = 0; i < 24; ++i) {
        #pragma unroll
        for (int j = 0; j < 4; ++j) {
            if (key[i * 4 + j] >= keyLo) {
                int s = atomicAdd(&candN, 1);
                if (s < MAXCAND) candIdx[s] = (tid + i * 256) * 4 + j;
            }
        }
    }
    __syncthreads();
    const int nc = candN < MAXCAND ? candN : MAXCAND;

    // ---- fp64 recompute of candidates: dot(ash, W_dec[idx,:]) ----
    {
        const int c = tid & 63, part = tid >> 6;
        double s = 0.0;
        if (c < nc) {
            const float* wr = W_dec + (size_t)candIdx[c] * K_DIM + part * 192;
            const float* ar = ash + part * 192;
            #pragma unroll 4
            for (int d = 0; d < 192; ++d) s += (double)ar[d] * (double)wr[d];
        }
        partsum[part][c] = s;
    }
    __syncthreads();
    if (tid < MAXCAND)
        candVal[tid] = partsum[0][tid] + partsum[1][tid] + partsum[2][tid] + partsum[3][tid];
    __syncthreads();

    // ---- rank candidates by (fp64 value desc, index asc); take top 32 ----
    if (tid < nc) {
        const double v = candVal[tid];
        const int    idx = candIdx[tid];
        int rank = 0;
        for (int t = 0; t < nc; ++t) {
            double vt2 = candVal[t]; int it = candIdx[t];
            if (vt2 > v || (vt2 == v && it < idx)) rank++;
        }
        if (rank < TOPK) { selIdx[rank] = idx; selVal[rank] = (float)v; }
    }
    __syncthreads();

    // ---- z row: dense zeros, then scatter the 32 selected ----
    float* zrow = z + (size_t)row * N_HID;
    const float4 zero4 = make_float4(0.f, 0.f, 0.f, 0.f);
    #pragma unroll
    for (int i = 0; i < 24; ++i)
        *(float4*)(zrow + ((size_t)(tid + i * 256) << 2)) = zero4;
    __syncthreads();
    if (tid < TOPK) zrow[selIdx[tid]] = selVal[tid];

    // ---- fused decode: recon[row,:] = sum_s val_s * W_dec[idx_s,:] + b_pre ----
    const int d0 = tid;
    float a0 = b_pre[d0], a1 = b_pre[d0 + 256], a2 = b_pre[d0 + 512];
    #pragma unroll 8
    for (int s = 0; s < TOPK; ++s) {
        const float v = selVal[s];
        const float* wr = W_dec + (size_t)selIdx[s] * K_DIM;
        a0 = fmaf(v, wr[d0], a0);
        a1 = fmaf(v, wr[d0 + 256], a1);
        a2 = fmaf(v, wr[d0 + 512], a2);
    }
    float* rrow = recon + (size_t)row * K_DIM;
    rrow[d0] = a0;
    rrow[d0 + 256] = a1;
    rrow[d0 + 512] = a2;
}

// ---------------------------------------------------------------------------
extern "C" void kernel_launch(void* const* d_in, const int* in_sizes, int n_in,
                              void* d_out, int out_size, void* d_ws, size_t ws_size,
                              hipStream_t stream) {
    const float* A     = (const float*)d_in[0];
    const float* W_enc = (const float*)d_in[1];
    const float* W_dec = (const float*)d_in[2];
    const float* b_pre = (const float*)d_in[3];

    float* recon = (float*)d_out;
    float* acts  = recon + (size_t)M_ROWS * K_DIM;
    float* zbuf  = acts + (size_t)M_ROWS * N_HID;

    dim3 g1(N_HID / 64, M_ROWS / 64);
    encode_gemm<<<g1, 256, 0, stream>>>(A, W_enc, b_pre, acts);
    topk_decode<<<M_ROWS, 256, 0, stream>>>(acts, A, W_dec, b_pre, zbuf, recon);
}